// Round 5
// baseline (83.761 us; speedup 1.0000x reference)
//
#include <hip/hip_runtime.h>
#include <hip/hip_bf16.h>

// Problem constants (hardcoded in the reference)
#define B_SZ 512
#define D_SZ 1024
#define NK 160
#define NCOL 480          // NK*3
#define OUTW 1184         // D + NK
#define LOG2E 1.44269504088896340736f
#define NBLK 512          // persistent grid: 2 blocks/CU on 256 CUs

typedef __attribute__((ext_vector_type(8))) short bf16x8;
typedef __attribute__((ext_vector_type(4))) float f32x4;

__device__ __forceinline__ unsigned int f32_bf16_rne(float f) {
    unsigned int u = __float_as_uint(f);
    u += 0x7fffu + ((u >> 16) & 1u);   // round-to-nearest-even at bf16 boundary
    return u >> 16;
}
__device__ __forceinline__ unsigned int pk2(float x, float y) {
    return f32_bf16_rne(x) | (f32_bf16_rne(y) << 16);
}
__device__ __forceinline__ float bf16u_to_f32(unsigned int h) {
    return __uint_as_float(h << 16);
}

// One persistent kernel: [copy + GEMM(on-the-fly cvt)] -> grid barrier -> [pairwise]
__global__ __launch_bounds__(256, 2) void mbd_fused_kernel(
    const float* __restrict__ A,      // [512][1024]
    const float* __restrict__ W,      // [1024][480]
    const float* __restrict__ bias,   // [480]
    float* __restrict__ out,          // [512][1184]
    float* __restrict__ act_t,        // ws: [480][512] f32, pre-scaled by log2e
    unsigned int* __restrict__ bar)   // ws: barrier counter (memset to 0 each call)
{
    __shared__ char lds[32768];       // GEMM: 2 bufs x (A 8K + Bh 4K + Bl 4K); pairwise: as4 8K + ps 1K
    const int bid = blockIdx.x;
    const int t = threadIdx.x;

    // ---- fused input copy: row bid -> out[:, 0:1024] (256 thr x float4 = 1024)
    {
        const float4 v = *reinterpret_cast<const float4*>(&A[bid * D_SZ + t * 4]);
        *reinterpret_cast<float4*>(&out[bid * OUTW + t * 4]) = v;
    }

    // ---- GEMM: tile 32(M) x 16(N), K-chunk 128, 4 waves.
    // waves 0,1 = rows 0-15/16-31 vs W-hi; waves 2,3 = same rows vs W-lo residual.
    if (bid < 480) {
        // XCD-aware swizzle: xcd=bid&7 owns bm {2x,2x+1} -> A rows L2-local per XCD
        const int g = bid >> 3;
        const int bm = (bid & 7) * 2 + (g & 1);   // 0..15
        const int bn = g >> 1;                    // 0..29
        const int i0 = bm * 32, c0 = bn * 16;
        const int w = __builtin_amdgcn_readfirstlane(t >> 6);  // 0..3 uniform
        const int l = t & 63, lhi = l >> 4, llo = l & 15;

        // staging roles (whole block): A: 32 rows x 8 segs of 16 f32; W: 16 cols x 16 kb of 8 k
        const int arow = t >> 3, aseg = t & 7;
        const int wcol = t >> 4, wkb = t & 15;
        const int aswz = (arow & 7) << 4;
        const int wswz = (wcol & 7) << 4;
        const float* __restrict__ aptr = A + (size_t)(i0 + arow) * D_SZ + aseg * 16;
        const float* __restrict__ wptr = W + (size_t)wkb * 8 * NCOL + (c0 + wcol);

        f32x4 acc = {0.f, 0.f, 0.f, 0.f};
        float4 ra[4];
        float rw[8];

        auto issue_loads = [&](int k0) {
#pragma unroll
            for (int s = 0; s < 4; ++s)
                ra[s] = *reinterpret_cast<const float4*>(aptr + k0 + s * 4);
#pragma unroll
            for (int j = 0; j < 8; ++j)
                rw[j] = wptr[(size_t)(k0 + j) * NCOL];   // one fully-used 64B line per k-row
        };
        auto write_stage = [&](int buf) {
            char* base = lds + buf * 16384;
            uint4 p0, p1;
            p0.x = pk2(ra[0].x, ra[0].y); p0.y = pk2(ra[0].z, ra[0].w);
            p0.z = pk2(ra[1].x, ra[1].y); p0.w = pk2(ra[1].z, ra[1].w);
            p1.x = pk2(ra[2].x, ra[2].y); p1.y = pk2(ra[2].z, ra[2].w);
            p1.z = pk2(ra[3].x, ra[3].y); p1.w = pk2(ra[3].z, ra[3].w);
            char* arp = base + arow * 256;
            *reinterpret_cast<uint4*>(arp + ((aseg * 32) ^ aswz)) = p0;
            *reinterpret_cast<uint4*>(arp + ((aseg * 32 + 16) ^ aswz)) = p1;
            unsigned int h[8]; float lo[8];
#pragma unroll
            for (int j = 0; j < 8; ++j) {
                h[j] = f32_bf16_rne(rw[j]);
                lo[j] = rw[j] - bf16u_to_f32(h[j]);
            }
            uint4 ph, pl;
            ph.x = h[0] | (h[1] << 16); ph.y = h[2] | (h[3] << 16);
            ph.z = h[4] | (h[5] << 16); ph.w = h[6] | (h[7] << 16);
            pl.x = pk2(lo[0], lo[1]); pl.y = pk2(lo[2], lo[3]);
            pl.z = pk2(lo[4], lo[5]); pl.w = pk2(lo[6], lo[7]);
            const int wo = (wkb * 16) ^ wswz;
            *reinterpret_cast<uint4*>(base + 8192 + wcol * 256 + wo) = ph;
            *reinterpret_cast<uint4*>(base + 12288 + wcol * 256 + wo) = pl;
        };
        auto compute = [&](int buf) {
            const char* base = lds + buf * 16384;
            const char* bsrc = base + ((w >= 2) ? 12288 : 8192);
            const int wrow = (w & 1) * 16;
#pragma unroll
            for (int ks = 0; ks < 4; ++ks) {
                const int koff = (lhi * 16 + ks * 64) ^ ((llo & 7) << 4);
                const bf16x8 af = *reinterpret_cast<const bf16x8*>(base + (wrow + llo) * 256 + koff);
                const bf16x8 bf = *reinterpret_cast<const bf16x8*>(bsrc + llo * 256 + koff);
                acc = __builtin_amdgcn_mfma_f32_16x16x32_bf16(af, bf, acc, 0, 0, 0);
            }
        };

        issue_loads(0);
        write_stage(0);
        __syncthreads();
        for (int ch = 0; ch < 8; ++ch) {
            if (ch < 7) issue_loads((ch + 1) * 128);   // in flight during MFMA
            compute(ch & 1);
            if (ch < 7) {
                __syncthreads();
                write_stage((ch + 1) & 1);
                __syncthreads();
            }
        }
        __syncthreads();
        // combine lo-residual into hi waves, epilogue store (C/D: col=lane&15, row=(lane>>4)*4+reg)
        float4* comb = reinterpret_cast<float4*>(lds);
        if (w >= 2) comb[(w - 2) * 64 + l] = make_float4(acc[0], acc[1], acc[2], acc[3]);
        __syncthreads();
        if (w < 2) {
            const float4 lo4 = comb[w * 64 + l];
            const int col = c0 + llo;
            const float bs = bias[col];
            float4 o;
            o.x = (acc[0] + lo4.x + bs) * LOG2E;
            o.y = (acc[1] + lo4.y + bs) * LOG2E;
            o.z = (acc[2] + lo4.z + bs) * LOG2E;
            o.w = (acc[3] + lo4.w + bs) * LOG2E;
            *reinterpret_cast<float4*>(&act_t[(size_t)col * B_SZ + i0 + (w & 1) * 16 + lhi * 4]) = o;
        }
    }

    // ---- grid barrier (all NBLK blocks; counter zeroed by memset node each call)
    __syncthreads();
    if (t == 0) {
        __hip_atomic_fetch_add(bar, 1u, __ATOMIC_ACQ_REL, __HIP_MEMORY_SCOPE_AGENT);
        while (__hip_atomic_load(bar, __ATOMIC_RELAXED, __HIP_MEMORY_SCOPE_AGENT) < (unsigned)NBLK)
            __builtin_amdgcn_s_sleep(8);
        (void)__hip_atomic_load(bar, __ATOMIC_ACQUIRE, __HIP_MEMORY_SCOPE_AGENT);
    }
    __syncthreads();

    // ---- pairwise: 2560 units = 160 k x 16 chunks(32 rows); exactly 5 units/block.
    // acts pre-scaled by log2e so exp(-d) == exp2(-d'); j==i gives +1 (matches ref).
    float4* as4 = reinterpret_cast<float4*>(lds);        // 512 x 16B
    float* ps = reinterpret_cast<float*>(lds + 8192);    // 256 partials
    for (int u = bid; u < NK * 16; u += NBLK) {
        const int k = u >> 4;
        const int chunk = u & 15;
        const float* __restrict__ p0 = act_t + (size_t)(3 * k + 0) * B_SZ;
        const float* __restrict__ p1 = act_t + (size_t)(3 * k + 1) * B_SZ;
        const float* __restrict__ p2 = act_t + (size_t)(3 * k + 2) * B_SZ;
        __syncthreads();   // previous unit's readers done before overwrite
#pragma unroll
        for (int s = 0; s < 2; ++s) {
            const int idx = t + s * 256;
            as4[idx] = make_float4(p0[idx], p1[idx], p2[idx], 0.f);
        }
        __syncthreads();
        const int r = t & 31, jseg = t >> 5;     // 32 rows x 8 j-segments of 64
        const float4 ai = as4[chunk * 32 + r];
        float acc = 0.f;
        const int j0 = jseg * 64;
#pragma unroll 8
        for (int jj = 0; jj < 64; ++jj) {
            const float4 av = as4[j0 + jj];       // 2-addr broadcast (free)
            const float d = fabsf(ai.x - av.x) + fabsf(ai.y - av.y) + fabsf(ai.z - av.z);
            acc += __builtin_amdgcn_exp2f(-d);
        }
        ps[t] = acc;
        __syncthreads();
        if (t < 32) {
            float ssum = ps[t];
#pragma unroll
            for (int s = 1; s < 8; ++s) ssum += ps[t + 32 * s];
            out[(size_t)(chunk * 32 + t) * OUTW + D_SZ + k] = ssum;
        }
    }
}

extern "C" void kernel_launch(void* const* d_in, const int* in_sizes, int n_in,
                              void* d_out, int out_size, void* d_ws, size_t ws_size,
                              hipStream_t stream)
{
    const float* inputs = (const float*)d_in[0];   // [512,1024] f32
    const float* W      = (const float*)d_in[1];   // [1024,480] f32
    const float* bias   = (const float*)d_in[2];   // [480] f32
    float* out = (float*)d_out;                    // [512,1184] f32

    char* ws = (char*)d_ws;
    float* act_t = (float*)ws;                                 // 983,040 B
    unsigned int* bar = (unsigned int*)(ws + 983040);          // 64 B barrier slot

    hipMemsetAsync(bar, 0, 64, stream);            // re-init barrier every call (graph-safe)
    mbd_fused_kernel<<<NBLK, 256, 0, stream>>>(inputs, W, bias, out, act_t, bar);
}

// Round 6
// 34.656 us; speedup vs baseline: 2.4169x; 2.4169x over previous
//
#include <hip/hip_runtime.h>
#include <hip/hip_bf16.h>

// Problem constants (hardcoded in the reference)
#define B_SZ 512
#define D_SZ 1024
#define NK 160
#define NCOL 480          // NK*3
#define OUTW 1184         // D + NK
#define LOG2E 1.44269504088896340736f

typedef __attribute__((ext_vector_type(8))) short bf16x8;
typedef __attribute__((ext_vector_type(4))) float f32x4;

__device__ __forceinline__ unsigned int f32_bf16_rne(float f) {
    unsigned int u = __float_as_uint(f);
    u += 0x7fffu + ((u >> 16) & 1u);   // round-to-nearest-even at bf16 boundary
    return u >> 16;
}
__device__ __forceinline__ unsigned int pk2(float x, float y) {
    return f32_bf16_rne(x) | (f32_bf16_rne(y) << 16);
}
__device__ __forceinline__ float bf16u_to_f32(unsigned int h) {
    return __uint_as_float(h << 16);
}

// ---------------- Dispatch 1: input->out copy + on-the-fly-convert MFMA GEMM.
// Tile 32(M) x 16(N), K-chunk 128, 4 waves. Waves 0,1: W-hi; waves 2,3: W-lo residual.
// act_t[col][i] = (A[i,:].W[:,col] + b[col]) * log2e.
__global__ __launch_bounds__(256) void mbd_gemm_kernel(
    const float* __restrict__ A,      // [512][1024]
    const float* __restrict__ W,      // [1024][480]
    const float* __restrict__ bias,   // [480]
    float* __restrict__ out,          // [512][1184]
    float* __restrict__ act_t)        // ws: [480][512] f32, pre-scaled by log2e
{
    __shared__ char lds[32768];       // 2 bufs x (A 8K + Bh 4K + Bl 4K)
    const int bid = blockIdx.x;
    const int t = threadIdx.x;

    // fused input copy: row bid -> out[:, 0:1024]
    {
        const float4 v = *reinterpret_cast<const float4*>(&A[bid * D_SZ + t * 4]);
        *reinterpret_cast<float4*>(&out[bid * OUTW + t * 4]) = v;
    }
    if (bid >= 480) return;

    // XCD-aware swizzle: xcd=bid&7 owns bm {2x,2x+1} -> A rows L2-local per XCD
    const int g = bid >> 3;
    const int bm = (bid & 7) * 2 + (g & 1);   // 0..15
    const int bn = g >> 1;                    // 0..29
    const int i0 = bm * 32, c0 = bn * 16;
    const int w = __builtin_amdgcn_readfirstlane(t >> 6);  // 0..3 uniform
    const int l = t & 63, lhi = l >> 4, llo = l & 15;

    // staging roles: A: 32 rows x 8 segs of 16 f32 (coalesced 128B runs);
    // W: 16 kb-groups x 16 cols -> lanes 0-15 = one fully-used 64B line.
    const int arow = t >> 3, aseg = t & 7;
    const int wcol = t & 15, wkb = t >> 4;     // SWAPPED vs r5: coalesced W reads
    const int aswz = (arow & 7) << 4;
    const int wswz = (wcol & 7) << 4;
    const float* __restrict__ aptr = A + (size_t)(i0 + arow) * D_SZ + aseg * 16;
    const float* __restrict__ wptr = W + (size_t)wkb * 8 * NCOL + (c0 + wcol);

    f32x4 acc = {0.f, 0.f, 0.f, 0.f};
    float4 ra[4];
    float rw[8];

    auto issue_loads = [&](int k0) {
#pragma unroll
        for (int s = 0; s < 4; ++s)
            ra[s] = *reinterpret_cast<const float4*>(aptr + k0 + s * 4);
#pragma unroll
        for (int j = 0; j < 8; ++j)
            rw[j] = wptr[(size_t)(k0 + j) * NCOL];
    };
    auto write_stage = [&](int buf) {
        char* base = lds + buf * 16384;
        uint4 p0, p1;
        p0.x = pk2(ra[0].x, ra[0].y); p0.y = pk2(ra[0].z, ra[0].w);
        p0.z = pk2(ra[1].x, ra[1].y); p0.w = pk2(ra[1].z, ra[1].w);
        p1.x = pk2(ra[2].x, ra[2].y); p1.y = pk2(ra[2].z, ra[2].w);
        p1.z = pk2(ra[3].x, ra[3].y); p1.w = pk2(ra[3].z, ra[3].w);
        char* arp = base + arow * 256;
        *reinterpret_cast<uint4*>(arp + ((aseg * 32) ^ aswz)) = p0;
        *reinterpret_cast<uint4*>(arp + ((aseg * 32 + 16) ^ aswz)) = p1;
        unsigned int h[8]; float lo[8];
#pragma unroll
        for (int j = 0; j < 8; ++j) {
            h[j] = f32_bf16_rne(rw[j]);
            lo[j] = rw[j] - bf16u_to_f32(h[j]);
        }
        uint4 ph, pl;
        ph.x = h[0] | (h[1] << 16); ph.y = h[2] | (h[3] << 16);
        ph.z = h[4] | (h[5] << 16); ph.w = h[6] | (h[7] << 16);
        pl.x = pk2(lo[0], lo[1]); pl.y = pk2(lo[2], lo[3]);
        pl.z = pk2(lo[4], lo[5]); pl.w = pk2(lo[6], lo[7]);
        const int wo = (wkb * 16) ^ wswz;
        *reinterpret_cast<uint4*>(base + 8192 + wcol * 256 + wo) = ph;
        *reinterpret_cast<uint4*>(base + 12288 + wcol * 256 + wo) = pl;
    };
    auto compute = [&](int buf) {
        const char* base = lds + buf * 16384;
        const char* bsrc = base + ((w >= 2) ? 12288 : 8192);
        const int wrow = (w & 1) * 16;
#pragma unroll
        for (int ks = 0; ks < 4; ++ks) {
            const int koff = (lhi * 16 + ks * 64) ^ ((llo & 7) << 4);
            const bf16x8 af = *reinterpret_cast<const bf16x8*>(base + (wrow + llo) * 256 + koff);
            const bf16x8 bf = *reinterpret_cast<const bf16x8*>(bsrc + llo * 256 + koff);
            acc = __builtin_amdgcn_mfma_f32_16x16x32_bf16(af, bf, acc, 0, 0, 0);
        }
    };

    issue_loads(0);
    write_stage(0);
    __syncthreads();
    for (int ch = 0; ch < 8; ++ch) {
        if (ch < 7) issue_loads((ch + 1) * 128);   // in flight during MFMA
        compute(ch & 1);
        if (ch < 7) {
            __syncthreads();
            write_stage((ch + 1) & 1);
            __syncthreads();
        }
    }
    __syncthreads();
    // combine lo-residual into hi waves; C/D layout: col=lane&15, row=(lane>>4)*4+reg
    float4* comb = reinterpret_cast<float4*>(lds);
    if (w >= 2) comb[(w - 2) * 64 + l] = make_float4(acc[0], acc[1], acc[2], acc[3]);
    __syncthreads();
    if (w < 2) {
        const float4 lo4 = comb[w * 64 + l];
        const int col = c0 + llo;
        const float bs = bias[col];
        float4 o;
        o.x = (acc[0] + lo4.x + bs) * LOG2E;
        o.y = (acc[1] + lo4.y + bs) * LOG2E;
        o.z = (acc[2] + lo4.z + bs) * LOG2E;
        o.w = (acc[3] + lo4.w + bs) * LOG2E;
        *reinterpret_cast<float4*>(&act_t[(size_t)col * B_SZ + i0 + (w & 1) * 16 + lhi * 4]) = o;
    }
}

// ---------------- Dispatch 2: pairwise. Grid (160,8) x 128 thr (2 waves).
// Unit = (k, 64-row chunk); lane pair (2r,2r+1) handles row r, j-halves 0/1.
// acts pre-scaled by log2e so exp(-d) == exp2(-d'); j==i gives +1 (matches ref).
__global__ __launch_bounds__(128) void mbd_pairwise_kernel(
    const float* __restrict__ act_t,   // [480][512] planes
    float* __restrict__ out)           // [512][1184]
{
    __shared__ float4 as4[B_SZ];
    const int k = blockIdx.x;          // 0..159
    const int c = blockIdx.y;          // 0..7
    const int t = threadIdx.x;         // 0..127

    const float* __restrict__ p0 = act_t + (size_t)(3 * k + 0) * B_SZ;
    const float* __restrict__ p1 = act_t + (size_t)(3 * k + 1) * B_SZ;
    const float* __restrict__ p2 = act_t + (size_t)(3 * k + 2) * B_SZ;
#pragma unroll
    for (int s = 0; s < 4; ++s) {
        const int idx = t + s * 128;
        as4[idx] = make_float4(p0[idx], p1[idx], p2[idx], 0.f);
    }
    __syncthreads();

    const int row = c * 64 + (t >> 1);
    const int jh = t & 1;
    const float4 ai = as4[row];
    float acc = 0.f;
    const int j0 = jh * 256;
#pragma unroll 8
    for (int jj = 0; jj < 256; ++jj) {
        const float4 av = as4[j0 + jj];   // 2-addr wave broadcast (free)
        const float d = fabsf(ai.x - av.x) + fabsf(ai.y - av.y) + fabsf(ai.z - av.z);
        acc += __builtin_amdgcn_exp2f(-d);
    }
    acc += __shfl_xor(acc, 1);            // combine the two j-halves (in-wave)
    if (jh == 0) out[(size_t)row * OUTW + D_SZ + k] = acc;
}

extern "C" void kernel_launch(void* const* d_in, const int* in_sizes, int n_in,
                              void* d_out, int out_size, void* d_ws, size_t ws_size,
                              hipStream_t stream)
{
    const float* inputs = (const float*)d_in[0];   // [512,1024] f32
    const float* W      = (const float*)d_in[1];   // [1024,480] f32
    const float* bias   = (const float*)d_in[2];   // [480] f32
    float* out = (float*)d_out;                    // [512,1184] f32
    float* act_t = (float*)d_ws;                   // [480][512] f32 = 983,040 B

    mbd_gemm_kernel<<<512, 256, 0, stream>>>(inputs, W, bias, out, act_t);
    mbd_pairwise_kernel<<<dim3(NK, 8), 128, 0, stream>>>(act_t, out);
}

// Round 7
// 26.974 us; speedup vs baseline: 3.1053x; 1.2848x over previous
//
#include <hip/hip_runtime.h>
#include <hip/hip_bf16.h>

// Problem constants (hardcoded in the reference)
#define B_SZ 512
#define D_SZ 1024
#define NK 160
#define NCOL 480          // NK*3
#define OUTW 1184         // D + NK
#define LOG2E 1.44269504088896340736f

typedef __attribute__((ext_vector_type(8))) short bf16x8;
typedef __attribute__((ext_vector_type(4))) float f32x4;

__device__ __forceinline__ unsigned int f32_bf16_rne(float f) {
    unsigned int u = __float_as_uint(f);
    u += 0x7fffu + ((u >> 16) & 1u);   // round-to-nearest-even at bf16 boundary
    return u >> 16;
}
__device__ __forceinline__ unsigned int pk2(float x, float y) {
    return f32_bf16_rne(x) | (f32_bf16_rne(y) << 16);
}
__device__ __forceinline__ float bf16u_to_f32(unsigned int h) {
    return __uint_as_float(h << 16);
}

// ---------------- Dispatch 1: input->out copy + on-the-fly-convert MFMA GEMM.
// (byte-identical logic to round 6 — single-variable experiment)
__global__ __launch_bounds__(256) void mbd_gemm_kernel(
    const float* __restrict__ A,      // [512][1024]
    const float* __restrict__ W,      // [1024][480]
    const float* __restrict__ bias,   // [480]
    float* __restrict__ out,          // [512][1184]
    float* __restrict__ act_t)        // ws: [480][512] f32, pre-scaled by log2e
{
    __shared__ char lds[32768];       // 2 bufs x (A 8K + Bh 4K + Bl 4K)
    const int bid = blockIdx.x;
    const int t = threadIdx.x;

    // fused input copy: row bid -> out[:, 0:1024]
    {
        const float4 v = *reinterpret_cast<const float4*>(&A[bid * D_SZ + t * 4]);
        *reinterpret_cast<float4*>(&out[bid * OUTW + t * 4]) = v;
    }
    if (bid >= 480) return;

    const int g = bid >> 3;
    const int bm = (bid & 7) * 2 + (g & 1);   // 0..15
    const int bn = g >> 1;                    // 0..29
    const int i0 = bm * 32, c0 = bn * 16;
    const int w = __builtin_amdgcn_readfirstlane(t >> 6);  // 0..3 uniform
    const int l = t & 63, lhi = l >> 4, llo = l & 15;

    const int arow = t >> 3, aseg = t & 7;
    const int wcol = t & 15, wkb = t >> 4;
    const int aswz = (arow & 7) << 4;
    const int wswz = (wcol & 7) << 4;
    const float* __restrict__ aptr = A + (size_t)(i0 + arow) * D_SZ + aseg * 16;
    const float* __restrict__ wptr = W + (size_t)wkb * 8 * NCOL + (c0 + wcol);

    f32x4 acc = {0.f, 0.f, 0.f, 0.f};
    float4 ra[4];
    float rw[8];

    auto issue_loads = [&](int k0) {
#pragma unroll
        for (int s = 0; s < 4; ++s)
            ra[s] = *reinterpret_cast<const float4*>(aptr + k0 + s * 4);
#pragma unroll
        for (int j = 0; j < 8; ++j)
            rw[j] = wptr[(size_t)(k0 + j) * NCOL];
    };
    auto write_stage = [&](int buf) {
        char* base = lds + buf * 16384;
        uint4 p0, p1;
        p0.x = pk2(ra[0].x, ra[0].y); p0.y = pk2(ra[0].z, ra[0].w);
        p0.z = pk2(ra[1].x, ra[1].y); p0.w = pk2(ra[1].z, ra[1].w);
        p1.x = pk2(ra[2].x, ra[2].y); p1.y = pk2(ra[2].z, ra[2].w);
        p1.z = pk2(ra[3].x, ra[3].y); p1.w = pk2(ra[3].z, ra[3].w);
        char* arp = base + arow * 256;
        *reinterpret_cast<uint4*>(arp + ((aseg * 32) ^ aswz)) = p0;
        *reinterpret_cast<uint4*>(arp + ((aseg * 32 + 16) ^ aswz)) = p1;
        unsigned int h[8]; float lo[8];
#pragma unroll
        for (int j = 0; j < 8; ++j) {
            h[j] = f32_bf16_rne(rw[j]);
            lo[j] = rw[j] - bf16u_to_f32(h[j]);
        }
        uint4 ph, pl;
        ph.x = h[0] | (h[1] << 16); ph.y = h[2] | (h[3] << 16);
        ph.z = h[4] | (h[5] << 16); ph.w = h[6] | (h[7] << 16);
        pl.x = pk2(lo[0], lo[1]); pl.y = pk2(lo[2], lo[3]);
        pl.z = pk2(lo[4], lo[5]); pl.w = pk2(lo[6], lo[7]);
        const int wo = (wkb * 16) ^ wswz;
        *reinterpret_cast<uint4*>(base + 8192 + wcol * 256 + wo) = ph;
        *reinterpret_cast<uint4*>(base + 12288 + wcol * 256 + wo) = pl;
    };
    auto compute = [&](int buf) {
        const char* base = lds + buf * 16384;
        const char* bsrc = base + ((w >= 2) ? 12288 : 8192);
        const int wrow = (w & 1) * 16;
#pragma unroll
        for (int ks = 0; ks < 4; ++ks) {
            const int koff = (lhi * 16 + ks * 64) ^ ((llo & 7) << 4);
            const bf16x8 af = *reinterpret_cast<const bf16x8*>(base + (wrow + llo) * 256 + koff);
            const bf16x8 bf = *reinterpret_cast<const bf16x8*>(bsrc + llo * 256 + koff);
            acc = __builtin_amdgcn_mfma_f32_16x16x32_bf16(af, bf, acc, 0, 0, 0);
        }
    };

    issue_loads(0);
    write_stage(0);
    __syncthreads();
    for (int ch = 0; ch < 8; ++ch) {
        if (ch < 7) issue_loads((ch + 1) * 128);   // in flight during MFMA
        compute(ch & 1);
        if (ch < 7) {
            __syncthreads();
            write_stage((ch + 1) & 1);
            __syncthreads();
        }
    }
    __syncthreads();
    // combine lo-residual into hi waves; C/D layout: col=lane&15, row=(lane>>4)*4+reg
    float4* comb = reinterpret_cast<float4*>(lds);
    if (w >= 2) comb[(w - 2) * 64 + l] = make_float4(acc[0], acc[1], acc[2], acc[3]);
    __syncthreads();
    if (w < 2) {
        const float4 lo4 = comb[w * 64 + l];
        const int col = c0 + llo;
        const float bs = bias[col];
        float4 o;
        o.x = (acc[0] + lo4.x + bs) * LOG2E;
        o.y = (acc[1] + lo4.y + bs) * LOG2E;
        o.z = (acc[2] + lo4.z + bs) * LOG2E;
        o.w = (acc[3] + lo4.w + bs) * LOG2E;
        *reinterpret_cast<float4*>(&act_t[(size_t)col * B_SZ + i0 + (w & 1) * 16 + lhi * 4]) = o;
    }
}

// ---------------- Dispatch 2: pairwise, 4 rows/lane, stride-8 j-interleave.
// 2560 blocks x 64 thr (10 waves/CU). Lane: rg=t&7 -> rows c*32+rg*4+{0..3},
// jq=t>>3 -> j in {jq, jq+8, ...}: 1 ds_read_b128 feeds 4 rows; the 8 distinct
// addresses/wave land on disjoint 4-bank groups -> conflict-free, no padding.
// acts pre-scaled by log2e so exp(-d)==exp2(-d'); j==i contributes +1 (as ref).
__global__ __launch_bounds__(64) void mbd_pairwise_kernel(
    const float* __restrict__ act_t,   // [480][512] planes
    float* __restrict__ out)           // [512][1184]
{
    __shared__ float4 as4[B_SZ];
    // XCD-bijective swizzle: 2560 = 8 XCD x 320; group the 16 same-k blocks
    // onto one XCD so act-plane reads are L2-local after first touch.
    const int bid = blockIdx.x;
    const int klin = (bid & 7) * 320 + (bid >> 3);
    const int k = klin >> 4;           // 0..159
    const int c = klin & 15;           // 0..15 (32-row chunk)
    const int t = threadIdx.x;         // 0..63

    const float* __restrict__ p0 = act_t + (size_t)(3 * k + 0) * B_SZ;
    const float* __restrict__ p1 = act_t + (size_t)(3 * k + 1) * B_SZ;
    const float* __restrict__ p2 = act_t + (size_t)(3 * k + 2) * B_SZ;
#pragma unroll
    for (int s = 0; s < 8; ++s) {
        const int idx = t + s * 64;
        as4[idx] = make_float4(p0[idx], p1[idx], p2[idx], 0.f);
    }
    __syncthreads();

    const int jq = t >> 3;             // 0..7 j-slice
    const int rg = t & 7;              // 0..7 row group
    const int r0 = c * 32 + rg * 4;
    const float4 a0 = as4[r0 + 0];
    const float4 a1 = as4[r0 + 1];
    const float4 a2 = as4[r0 + 2];
    const float4 a3 = as4[r0 + 3];

    float acc0 = 0.f, acc1 = 0.f, acc2 = 0.f, acc3 = 0.f;
#pragma unroll 8
    for (int jj = 0; jj < 64; ++jj) {
        const float4 av = as4[jq + jj * 8];
        acc0 += __builtin_amdgcn_exp2f(-(fabsf(a0.x - av.x) + fabsf(a0.y - av.y) + fabsf(a0.z - av.z)));
        acc1 += __builtin_amdgcn_exp2f(-(fabsf(a1.x - av.x) + fabsf(a1.y - av.y) + fabsf(a1.z - av.z)));
        acc2 += __builtin_amdgcn_exp2f(-(fabsf(a2.x - av.x) + fabsf(a2.y - av.y) + fabsf(a2.z - av.z)));
        acc3 += __builtin_amdgcn_exp2f(-(fabsf(a3.x - av.x) + fabsf(a3.y - av.y) + fabsf(a3.z - av.z)));
    }
    // reduce the 8 j-slices (lane bits 3..5)
#pragma unroll
    for (int m = 8; m <= 32; m <<= 1) {
        acc0 += __shfl_xor(acc0, m);
        acc1 += __shfl_xor(acc1, m);
        acc2 += __shfl_xor(acc2, m);
        acc3 += __shfl_xor(acc3, m);
    }
    if (t < 8) {
        out[(size_t)(r0 + 0) * OUTW + D_SZ + k] = acc0;
        out[(size_t)(r0 + 1) * OUTW + D_SZ + k] = acc1;
        out[(size_t)(r0 + 2) * OUTW + D_SZ + k] = acc2;
        out[(size_t)(r0 + 3) * OUTW + D_SZ + k] = acc3;
    }
}

extern "C" void kernel_launch(void* const* d_in, const int* in_sizes, int n_in,
                              void* d_out, int out_size, void* d_ws, size_t ws_size,
                              hipStream_t stream)
{
    const float* inputs = (const float*)d_in[0];   // [512,1024] f32
    const float* W      = (const float*)d_in[1];   // [1024,480] f32
    const float* bias   = (const float*)d_in[2];   // [480] f32
    float* out = (float*)d_out;                    // [512,1184] f32
    float* act_t = (float*)d_ws;                   // [480][512] f32 = 983,040 B

    mbd_gemm_kernel<<<512, 256, 0, stream>>>(inputs, W, bias, out, act_t);
    mbd_pairwise_kernel<<<NK * 16, 64, 0, stream>>>(act_t, out);
}